// Round 7
// baseline (432.857 us; speedup 1.0000x reference)
//
#include <hip/hip_runtime.h>
#include <stdint.h>
#include <math.h>

// W8A8 int8 GEMM, y = x @ W^T (int32) + rint(bias), out fp32.
// M=8192, N=4096, K=4096. Inputs arrive int32-encoded; pack pass -> int8 in d_ws.
// GEMM: 256x256 tile, 4-phase/K-tile schedule, distance-2 prefetch inside a
// double buffer (B(t+2) staged at P3, A(t+2) at P4 -- regions dead by then),
// counted vmcnt(8), T5 setprio, mfma_i32_16x16x64_i8, k-slot-major LDS
// (conflict-free, 0 measured). 8 waves = 2M x 4N, per-wave out 128x64, BK=128B.

typedef int i32x4 __attribute__((ext_vector_type(4)));

static constexpr int Mdim = 8192;
static constexpr int Ndim = 4096;
static constexpr int Kdim = 4096;
static constexpr int BM = 256;
static constexpr int BN = 256;
static constexpr int BKb = 128;             // K bytes per tile step
static constexpr int NKT = Kdim / BKb;      // 32 K-tiles
// Per-buffer LDS: A [2 half][8 kslot][128 row][16B] = 32KB, B same at +32768.
static constexpr int BUF_BYTES = 65536;

typedef const __attribute__((address_space(1))) unsigned int gu32;
typedef __attribute__((address_space(3))) unsigned int lu32;

__device__ __forceinline__ void gload_lds16(const int8_t* g, char* l) {
    __builtin_amdgcn_global_load_lds((gu32*)g, (lu32*)l, 16, 0, 0);
}

// ---- pack: int32 (values in [-127,127)) -> int8; X then W in one launch ----
__global__ void pack_i32_to_i8_both(const int* __restrict__ X32,
                                    const int* __restrict__ W32,
                                    unsigned int* __restrict__ Xp,
                                    unsigned int* __restrict__ Wp,
                                    int nX4, int nT4) {
    int idx = blockIdx.x * blockDim.x + threadIdx.x;
    int stride = gridDim.x * blockDim.x;
    for (int i = idx; i < nT4; i += stride) {
        const int* src; unsigned int* dst; int j;
        if (i < nX4) { src = X32; dst = Xp; j = i; }
        else         { src = W32; dst = Wp; j = i - nX4; }
        i32x4 v = ((const i32x4*)src)[j];
        unsigned int o = ((unsigned)v[0] & 0xffu)
                       | (((unsigned)v[1] & 0xffu) << 8)
                       | (((unsigned)v[2] & 0xffu) << 16)
                       | (((unsigned)v[3]) << 24);
        dst[j] = o;
    }
}

__global__ __launch_bounds__(512, 2) void w8a8_gemm_256(
    const int8_t* __restrict__ X, const int8_t* __restrict__ Wt,
    const float* __restrict__ bias, float* __restrict__ out)
{
    __shared__ char smem[2 * BUF_BYTES];   // 128 KiB

    const int tid = threadIdx.x;
    const int w   = tid >> 6;     // wave 0..7
    const int l   = tid & 63;
    const int fr  = l & 15;       // frag row/col
    const int fk  = l >> 4;       // k-group 0..3 (16B each)
    const int wm  = w >> 2;       // wave M 0..1 -> rows wm*128..+127
    const int wn  = w & 3;        // wave N 0..3 -> cols wn*64..+63

    const int bm = blockIdx.x * BM;
    const int bn = blockIdx.y * BN;

    // staging bases: wave w stages kslot w; lane l walks rows
    const int8_t* gA = X  + (size_t)(bm + l) * Kdim + w * 16;
    const int8_t* gB = Wt + (size_t)(bn + l) * Kdim + w * 16;
    const int ldsAw = w * 2048 + l * 16;           // + hm*16384 + s*1024 + buf
    const int ldsBw = 32768 + w * 2048 + l * 16;

    auto stageA = [&](int t, int hm) {
        const int bufo = (t & 1) * BUF_BYTES;
        const size_t ko = (size_t)t * BKb;
#pragma unroll
        for (int s = 0; s < 2; ++s)
            gload_lds16(gA + (size_t)(hm * 128 + s * 64) * Kdim + ko,
                        &smem[bufo + hm * 16384 + s * 1024 + ldsAw]);
    };
    auto stageB = [&](int t, int hn) {
        const int bufo = (t & 1) * BUF_BYTES;
        const size_t ko = (size_t)t * BKb;
#pragma unroll
        for (int s = 0; s < 2; ++s)
            gload_lds16(gB + (size_t)(hn * 128 + s * 64) * Kdim + ko,
                        &smem[bufo + hn * 16384 + s * 1024 + ldsBw]);
    };

    // fragment read bases (k-slot-major: [half][kslot][row][16B])
    const int aBase = wm * 16384 + fk * 2048 + fr * 16;
    const int bBase = 32768 + (wn >> 1) * 16384 + fk * 2048
                    + ((wn & 1) * 64 + fr) * 16;

    i32x4 acc[8][4] = {};
    i32x4 a[4][2], b[4][2];

    // ---- prologue: stage tiles 0 and 1 (16 loads); wait tile 0 (leave 8) ----
    stageB(0, 0); stageB(0, 1); stageA(0, 0); stageA(0, 1);
    stageB(1, 0); stageB(1, 1); stageA(1, 0); stageA(1, 1);
    asm volatile("s_waitcnt vmcnt(8)" ::: "memory");   // tile 0 fully landed
    __syncthreads();

    for (int t = 0; t < NKT; ++t) {
        const int p = (t & 1) * BUF_BYTES;

        // ---- P1: quadrant mi 0-3 x ni 0-1 (no staging) ----
#pragma unroll
        for (int ks = 0; ks < 2; ++ks) {
#pragma unroll
            for (int j = 0; j < 4; ++j)
                a[j][ks] = *(const i32x4*)&smem[p + aBase + ks * 8192 + j * 256];
#pragma unroll
            for (int ni = 0; ni < 2; ++ni)
                b[ni][ks] = *(const i32x4*)&smem[p + bBase + ks * 8192 + ni * 256];
        }
        __builtin_amdgcn_s_barrier();
        asm volatile("s_waitcnt lgkmcnt(0)" ::: "memory");
        __builtin_amdgcn_sched_barrier(0);
        __builtin_amdgcn_s_setprio(1);
#pragma unroll
        for (int ks = 0; ks < 2; ++ks)
#pragma unroll
            for (int j = 0; j < 4; ++j)
#pragma unroll
                for (int ni = 0; ni < 2; ++ni)
                    acc[j][ni] = __builtin_amdgcn_mfma_i32_16x16x64_i8(
                        a[j][ks], b[ni][ks], acc[j][ni], 0, 0, 0);
        __builtin_amdgcn_s_setprio(0);
        __builtin_amdgcn_s_barrier();

        // ---- P2: quadrant mi 0-3 x ni 2-3 (no staging) ----
#pragma unroll
        for (int ks = 0; ks < 2; ++ks)
#pragma unroll
            for (int ni = 2; ni < 4; ++ni)
                b[ni][ks] = *(const i32x4*)&smem[p + bBase + ks * 8192 + ni * 256];
        __builtin_amdgcn_s_barrier();
        asm volatile("s_waitcnt lgkmcnt(0)" ::: "memory");
        __builtin_amdgcn_sched_barrier(0);
        __builtin_amdgcn_s_setprio(1);
#pragma unroll
        for (int ks = 0; ks < 2; ++ks)
#pragma unroll
            for (int j = 0; j < 4; ++j)
#pragma unroll
                for (int ni = 2; ni < 4; ++ni)
                    acc[j][ni] = __builtin_amdgcn_mfma_i32_16x16x64_i8(
                        a[j][ks], b[ni][ks], acc[j][ni], 0, 0, 0);
        __builtin_amdgcn_s_setprio(0);
        __builtin_amdgcn_s_barrier();

        // ---- P3: quadrant mi 4-7 x ni 0-1; stage B(t+2) (B regions of this
        //          buffer are dead after P2's barrier) ----
#pragma unroll
        for (int ks = 0; ks < 2; ++ks)
#pragma unroll
            for (int j = 0; j < 4; ++j)
                a[j][ks] = *(const i32x4*)&smem[p + aBase + ks * 8192 + 1024 + j * 256];
        if (t + 2 < NKT) { stageB(t + 2, 0); stageB(t + 2, 1); }
        __builtin_amdgcn_s_barrier();
        asm volatile("s_waitcnt lgkmcnt(0)" ::: "memory");
        __builtin_amdgcn_sched_barrier(0);
        __builtin_amdgcn_s_setprio(1);
#pragma unroll
        for (int ks = 0; ks < 2; ++ks)
#pragma unroll
            for (int j = 0; j < 4; ++j)
#pragma unroll
                for (int ni = 0; ni < 2; ++ni)
                    acc[4 + j][ni] = __builtin_amdgcn_mfma_i32_16x16x64_i8(
                        a[j][ks], b[ni][ks], acc[4 + j][ni], 0, 0, 0);
        __builtin_amdgcn_s_setprio(0);
        __builtin_amdgcn_s_barrier();

        // ---- P4: quadrant mi 4-7 x ni 2-3; stage A(t+2) (A region dead
        //          after P3's barrier); counted wait for tile t+1 ----
        if (t + 2 < NKT) { stageA(t + 2, 0); stageA(t + 2, 1); }
        __builtin_amdgcn_sched_barrier(0);   // keep stage issue ahead of MFMA
        __builtin_amdgcn_s_setprio(1);
#pragma unroll
        for (int ks = 0; ks < 2; ++ks)
#pragma unroll
            for (int j = 0; j < 4; ++j)
#pragma unroll
                for (int ni = 2; ni < 4; ++ni)
                    acc[4 + j][ni] = __builtin_amdgcn_mfma_i32_16x16x64_i8(
                        a[j][ks], b[ni][ks], acc[4 + j][ni], 0, 0, 0);
        __builtin_amdgcn_s_setprio(0);
        // steady state: 16 outstanding (t+1: 8, t+2: 8) -> vmcnt(8) = t+1 done.
        if (t + 2 < NKT)      asm volatile("s_waitcnt vmcnt(8)" ::: "memory");
        else if (t + 1 < NKT) asm volatile("s_waitcnt vmcnt(0)" ::: "memory");
        __builtin_amdgcn_s_barrier();
    }

    // ---- epilogue: C/D col=lane&15, row=(lane>>4)*4+reg ----
    float bv[4];
#pragma unroll
    for (int ni = 0; ni < 4; ++ni)
        bv[ni] = rintf(bias[bn + wn * 64 + ni * 16 + fr]);
#pragma unroll
    for (int mi = 0; mi < 8; ++mi) {
        const int rbase = bm + wm * 128 + mi * 16 + fk * 4;
#pragma unroll
        for (int ni = 0; ni < 4; ++ni) {
            const int col = bn + wn * 64 + ni * 16 + fr;
#pragma unroll
            for (int r = 0; r < 4; ++r)
                out[(size_t)(rbase + r) * Ndim + col] = (float)acc[mi][ni][r] + bv[ni];
        }
    }
}

extern "C" void kernel_launch(void* const* d_in, const int* in_sizes, int n_in,
                              void* d_out, int out_size, void* d_ws, size_t ws_size,
                              hipStream_t stream) {
    const int*   X32  = (const int*)d_in[0];   // [8192,4096] int8 values as int32
    const int*   W32  = (const int*)d_in[1];   // [4096,4096] int8 values as int32
    const float* bias = (const float*)d_in[2]; // [4096] fp32
    float* out = (float*)d_out;                // [8192,4096] fp32

    int8_t* Xp = (int8_t*)d_ws;                          // 32 MB
    int8_t* Wp = (int8_t*)d_ws + (size_t)Mdim * Kdim;    // 16 MB

    const int nX4 = Mdim * Kdim / 4;
    const int nW4 = Ndim * Kdim / 4;
    pack_i32_to_i8_both<<<4096, 256, 0, stream>>>(
        X32, W32, (unsigned int*)Xp, (unsigned int*)Wp, nX4, nX4 + nW4);

    dim3 grid(Mdim / BM, Ndim / BN);  // 32 x 16
    w8a8_gemm_256<<<grid, dim3(512), 0, stream>>>(Xp, Wp, bias, out);
}

// Round 9
// 415.052 us; speedup vs baseline: 1.0429x; 1.0429x over previous
//
#include <hip/hip_runtime.h>
#include <stdint.h>
#include <math.h>

// W8A8 int8 GEMM, y = x @ W^T (int32) + rint(bias), out fp32.
// M=8192, N=4096, K=4096. Inputs arrive int32-encoded; pack pass -> int8 in d_ws.
// GEMM: 256x256 tile, register-pipelined 4-quadrant schedule: each quadrant's
// ds_reads are issued BEFORE the prior quadrant's MFMA and drain under it
// (breaks the barrier-lockstep that capped MfmaUtil at ~33%). Only 2 barriers
// per K-step (WAR guards). Staging: A(t+1)@Q1/Q2, B(t+2)@Q3, vmcnt(4).
// mfma_i32_16x16x64_i8, k-slot-major LDS (0 conflicts measured).
// 8 waves = 2M x 4N, per-wave out 128x64, BK=128B, LDS 128 KiB 2-dbuf.

typedef int i32x4 __attribute__((ext_vector_type(4)));

static constexpr int Mdim = 8192;
static constexpr int Ndim = 4096;
static constexpr int Kdim = 4096;
static constexpr int BM = 256;
static constexpr int BN = 256;
static constexpr int BKb = 128;             // K bytes per tile step
static constexpr int NKT = Kdim / BKb;      // 32 K-steps
static constexpr int BUF_BYTES = 65536;     // A 32KB + B 32KB per buffer

typedef const __attribute__((address_space(1))) unsigned int gu32;
typedef __attribute__((address_space(3))) unsigned int lu32;

__device__ __forceinline__ void gload_lds16(const int8_t* g, char* l) {
    __builtin_amdgcn_global_load_lds((gu32*)g, (lu32*)l, 16, 0, 0);
}

#define LGKM0_FENCE()  do { asm volatile("s_waitcnt lgkmcnt(0)" ::: "memory"); \
                            __builtin_amdgcn_sched_barrier(0); } while (0)

// ---- pack: int32 (values in [-127,127)) -> int8; X then W in one launch ----
__global__ void pack_i32_to_i8_both(const int* __restrict__ X32,
                                    const int* __restrict__ W32,
                                    unsigned int* __restrict__ Xp,
                                    unsigned int* __restrict__ Wp,
                                    int nX4, int nT4) {
    int idx = blockIdx.x * blockDim.x + threadIdx.x;
    int stride = gridDim.x * blockDim.x;
    for (int i = idx; i < nT4; i += stride) {
        const int* src; unsigned int* dst; int j;
        if (i < nX4) { src = X32; dst = Xp; j = i; }
        else         { src = W32; dst = Wp; j = i - nX4; }
        i32x4 v = ((const i32x4*)src)[j];
        unsigned int o = ((unsigned)v[0] & 0xffu)
                       | (((unsigned)v[1] & 0xffu) << 8)
                       | (((unsigned)v[2] & 0xffu) << 16)
                       | (((unsigned)v[3]) << 24);
        dst[j] = o;
    }
}

__global__ __launch_bounds__(512, 2) void w8a8_gemm_256(
    const int8_t* __restrict__ X, const int8_t* __restrict__ Wt,
    const float* __restrict__ bias, float* __restrict__ out)
{
    __shared__ char smem[2 * BUF_BYTES];   // 128 KiB

    const int tid = threadIdx.x;
    const int w   = tid >> 6;     // wave 0..7
    const int l   = tid & 63;
    const int fr  = l & 15;       // frag row/col
    const int fk  = l >> 4;       // k-group 0..3 (16B each)
    const int wm  = w >> 2;       // wave M 0..1 -> rows wm*128..+127
    const int wn  = w & 3;        // wave N 0..3 -> cols wn*64..+63

    const int bm = blockIdx.x * BM;
    const int bn = blockIdx.y * BN;

    // staging: wave w stages kslot w; lane l walks rows (linear LDS dest)
    const int8_t* gA = X  + (size_t)(bm + l) * Kdim + w * 16;
    const int8_t* gB = Wt + (size_t)(bn + l) * Kdim + w * 16;
    const int ldsAw = w * 2048 + l * 16;
    const int ldsBw = 32768 + w * 2048 + l * 16;

    auto stageA = [&](int t, int hm) {
        const int bufo = (t & 1) * BUF_BYTES;
        const size_t ko = (size_t)t * BKb;
#pragma unroll
        for (int s = 0; s < 2; ++s)
            gload_lds16(gA + (size_t)(hm * 128 + s * 64) * Kdim + ko,
                        &smem[bufo + hm * 16384 + s * 1024 + ldsAw]);
    };
    auto stageB = [&](int t, int hn) {
        const int bufo = (t & 1) * BUF_BYTES;
        const size_t ko = (size_t)t * BKb;
#pragma unroll
        for (int s = 0; s < 2; ++s)
            gload_lds16(gB + (size_t)(hn * 128 + s * 64) * Kdim + ko,
                        &smem[bufo + hn * 16384 + s * 1024 + ldsBw]);
    };

    // fragment read bases (k-slot-major: [half][kslot][128row][16B])
    const int aBase = wm * 16384 + fk * 2048 + fr * 16;
    const int bBase = 32768 + (wn >> 1) * 16384 + fk * 2048
                    + ((wn & 1) * 64 + fr) * 16;

    i32x4 acc[8][4] = {};
    i32x4 a03[4][2], a47[4][2], b01[2][2], b23[2][2];

#define RD_A03(P) do { _Pragma("unroll") for (int ks = 0; ks < 2; ++ks) \
    _Pragma("unroll") for (int j = 0; j < 4; ++j) \
        a03[j][ks] = *(const i32x4*)&smem[(P) + aBase + ks * 8192 + j * 256]; } while (0)
#define RD_A47(P) do { _Pragma("unroll") for (int ks = 0; ks < 2; ++ks) \
    _Pragma("unroll") for (int j = 0; j < 4; ++j) \
        a47[j][ks] = *(const i32x4*)&smem[(P) + aBase + ks * 8192 + 1024 + j * 256]; } while (0)
#define RD_B01(P) do { _Pragma("unroll") for (int ks = 0; ks < 2; ++ks) \
    _Pragma("unroll") for (int ni = 0; ni < 2; ++ni) \
        b01[ni][ks] = *(const i32x4*)&smem[(P) + bBase + ks * 8192 + ni * 256]; } while (0)
#define RD_B23(P) do { _Pragma("unroll") for (int ks = 0; ks < 2; ++ks) \
    _Pragma("unroll") for (int ni = 0; ni < 2; ++ni) \
        b23[ni][ks] = *(const i32x4*)&smem[(P) + bBase + ks * 8192 + (2 + ni) * 256]; } while (0)

#define MFMA_Q(AF, BF, MO, NO) do { __builtin_amdgcn_s_setprio(1); \
    _Pragma("unroll") for (int ks = 0; ks < 2; ++ks) \
    _Pragma("unroll") for (int j = 0; j < 4; ++j) \
    _Pragma("unroll") for (int ni = 0; ni < 2; ++ni) \
        acc[(MO) + j][(NO) + ni] = __builtin_amdgcn_mfma_i32_16x16x64_i8( \
            AF[j][ks], BF[ni][ks], acc[(MO) + j][(NO) + ni], 0, 0, 0); \
    __builtin_amdgcn_s_setprio(0); } while (0)

    // ---- prologue: stage tile0 (8) + B(1) (4); confirm tile0; preload Q1 frags
    stageB(0, 0); stageB(0, 1); stageA(0, 0); stageA(0, 1);
    stageB(1, 0); stageB(1, 1);
    asm volatile("s_waitcnt vmcnt(4)" ::: "memory");   // tile0 landed
    __syncthreads();
    RD_A03(0); RD_B01(0);

#pragma unroll 1
    for (int t = 0; t < NKT; ++t) {
        const int p  = (t & 1) * BUF_BYTES;
        const int pn = ((t + 1) & 1) * BUF_BYTES;

        // ---- Q1: acc[0-3][0-1] = a03 x b01 ; b23 reads drain under MFMA ----
        LGKM0_FENCE();                         // a03,b01 (prefetched) landed
        RD_B23(p);
        if (t + 1 < NKT) stageA(t + 1, 0);
        __builtin_amdgcn_sched_barrier(0);     // reads/stages issue before MFMA
        MFMA_Q(a03, b01, 0, 0);

        // ---- Q2: acc[0-3][2-3] = a03 x b23 ; a47 reads drain under MFMA ----
        LGKM0_FENCE();                         // b23 landed
        RD_A47(p);
        if (t + 1 < NKT) stageA(t + 1, 1);
        __builtin_amdgcn_sched_barrier(0);
        MFMA_Q(a03, b23, 0, 2);
        __builtin_amdgcn_s_barrier();          // all waves' B-p reads complete
                                               // -> B-p region safely dead

        // ---- Q3: acc[4-7][0-1] = a47 x b01 ; stage B(t+2) into dead region --
        LGKM0_FENCE();                         // a47 landed
        if (t + 2 < NKT) { stageB(t + 2, 0); stageB(t + 2, 1); }
        __builtin_amdgcn_sched_barrier(0);
        MFMA_Q(a47, b01, 4, 0);
        // counted wait: leave only B(t+2) in flight; t+1 fully landed
        if (t + 2 < NKT)      asm volatile("s_waitcnt vmcnt(4)" ::: "memory");
        else if (t + 1 < NKT) asm volatile("s_waitcnt vmcnt(0)" ::: "memory");
        __builtin_amdgcn_s_barrier();          // buffer pn ready for all waves

        // ---- Q4: acc[4-7][2-3] = a47 x b23 ; prefetch next-step Q1 frags ----
        if (t + 1 < NKT) { RD_A03(pn); RD_B01(pn); }
        __builtin_amdgcn_sched_barrier(0);
        MFMA_Q(a47, b23, 4, 2);
    }

    // ---- epilogue: C/D col=lane&15, row=(lane>>4)*4+reg ----
    float bv[4];
#pragma unroll
    for (int ni = 0; ni < 4; ++ni)
        bv[ni] = rintf(bias[bn + wn * 64 + ni * 16 + fr]);
#pragma unroll
    for (int mi = 0; mi < 8; ++mi) {
        const int rbase = bm + wm * 128 + mi * 16 + fk * 4;
#pragma unroll
        for (int ni = 0; ni < 4; ++ni) {
            const int col = bn + wn * 64 + ni * 16 + fr;
#pragma unroll
            for (int r = 0; r < 4; ++r)
                out[(size_t)(rbase + r) * Ndim + col] = (float)acc[mi][ni][r] + bv[ni];
        }
    }
}

extern "C" void kernel_launch(void* const* d_in, const int* in_sizes, int n_in,
                              void* d_out, int out_size, void* d_ws, size_t ws_size,
                              hipStream_t stream) {
    const int*   X32  = (const int*)d_in[0];   // [8192,4096] int8 values as int32
    const int*   W32  = (const int*)d_in[1];   // [4096,4096] int8 values as int32
    const float* bias = (const float*)d_in[2]; // [4096] fp32
    float* out = (float*)d_out;                // [8192,4096] fp32

    int8_t* Xp = (int8_t*)d_ws;                          // 32 MB
    int8_t* Wp = (int8_t*)d_ws + (size_t)Mdim * Kdim;    // 16 MB

    const int nX4 = Mdim * Kdim / 4;
    const int nW4 = Ndim * Kdim / 4;
    pack_i32_to_i8_both<<<4096, 256, 0, stream>>>(
        X32, W32, (unsigned int*)Xp, (unsigned int*)Wp, nX4, nX4 + nW4);

    dim3 grid(Mdim / BM, Ndim / BN);  // 32 x 16
    w8a8_gemm_256<<<grid, dim3(512), 0, stream>>>(Xp, Wp, bias, out);
}

// Round 10
// 414.025 us; speedup vs baseline: 1.0455x; 1.0025x over previous
//
#include <hip/hip_runtime.h>
#include <stdint.h>
#include <math.h>

// W8A8 int8 GEMM, y = x @ W^T (int32) + rint(bias), out fp32.
// M=8192, N=4096, K=4096. Inputs arrive int32-encoded; pack pass -> int8 in d_ws.
// R9 change: mfma_i32_32x32x32_i8 (32 insts/K-tile vs 64 for 16x16x64; tests
// per-instruction issue-overhead hypothesis after 3 schedules all hit ~33%)
// + bijective XCD swizzle (T1). Skeleton unchanged from R7: 256x256 tile,
// register-pipelined 4-quadrant schedule, 2 barriers/K-step, vmcnt(4),
// k-slot-major LDS [8 kslot][256 row][16B] (stride-16B b128 reads, 0 conflicts).
// 8 waves = 2M x 4N, per-wave out 128x64, BK=128B, LDS 128 KiB 2-dbuf.

typedef int i32x4 __attribute__((ext_vector_type(4)));
typedef int i32x16 __attribute__((ext_vector_type(16)));

static constexpr int Mdim = 8192;
static constexpr int Ndim = 4096;
static constexpr int Kdim = 4096;
static constexpr int BM = 256;
static constexpr int BN = 256;
static constexpr int BKb = 128;             // K bytes per tile step
static constexpr int NKT = Kdim / BKb;      // 32 K-steps
static constexpr int BUF_BYTES = 65536;     // A 32KB + B 32KB per buffer

typedef const __attribute__((address_space(1))) unsigned int gu32;
typedef __attribute__((address_space(3))) unsigned int lu32;

__device__ __forceinline__ void gload_lds16(const int8_t* g, char* l) {
    __builtin_amdgcn_global_load_lds((gu32*)g, (lu32*)l, 16, 0, 0);
}

#define LGKM0_FENCE()  do { asm volatile("s_waitcnt lgkmcnt(0)" ::: "memory"); \
                            __builtin_amdgcn_sched_barrier(0); } while (0)

// ---- pack: int32 (values in [-127,127)) -> int8; X then W in one launch ----
__global__ void pack_i32_to_i8_both(const int* __restrict__ X32,
                                    const int* __restrict__ W32,
                                    unsigned int* __restrict__ Xp,
                                    unsigned int* __restrict__ Wp,
                                    int nX4, int nT4) {
    int idx = blockIdx.x * blockDim.x + threadIdx.x;
    int stride = gridDim.x * blockDim.x;
    for (int i = idx; i < nT4; i += stride) {
        const int* src; unsigned int* dst; int j;
        if (i < nX4) { src = X32; dst = Xp; j = i; }
        else         { src = W32; dst = Wp; j = i - nX4; }
        i32x4 v = ((const i32x4*)src)[j];
        unsigned int o = ((unsigned)v[0] & 0xffu)
                       | (((unsigned)v[1] & 0xffu) << 8)
                       | (((unsigned)v[2] & 0xffu) << 16)
                       | (((unsigned)v[3]) << 24);
        dst[j] = o;
    }
}

__global__ __launch_bounds__(512, 2) void w8a8_gemm_256(
    const int8_t* __restrict__ X, const int8_t* __restrict__ Wt,
    const float* __restrict__ bias, float* __restrict__ out)
{
    __shared__ char smem[2 * BUF_BYTES];   // 128 KiB

    const int tid  = threadIdx.x;
    const int w    = tid >> 6;    // wave 0..7
    const int l    = tid & 63;
    const int lrow = l & 31;      // 32x32 frag row/col
    const int kh   = l >> 5;      // k-half 0/1 (16B each of K=32)
    const int wm   = w >> 2;      // wave M 0..1 -> rows wm*128..+127
    const int wn   = w & 3;       // wave N 0..3 -> cols wn*64..+63

    // ---- XCD-aware bijective swizzle (nwg=512, 512%8==0 -> simple form) ----
    const int bid = blockIdx.y * gridDim.x + blockIdx.x;   // 0..511
    const int swz = (bid & 7) * 64 + (bid >> 3);
    const int bm  = (swz & 31) * BM;    // bx = swz%32
    const int bn  = (swz >> 5) * BN;    // by = swz/32

    // staging: wave w stages kslot w (kslot = kinst*2 + khalf); lane walks rows
    const int8_t* gA = X  + (size_t)(bm + l) * Kdim + w * 16;
    const int8_t* gB = Wt + (size_t)(bn + l) * Kdim + w * 16;
    const int ldsAw = w * 4096 + l * 16;            // [kslot][256 row][16B]
    const int ldsBw = 32768 + w * 4096 + l * 16;

    auto stageA = [&](int t, int h) {               // h: row-half (128 rows)
        const int bufo = (t & 1) * BUF_BYTES;
        const size_t ko = (size_t)t * BKb;
#pragma unroll
        for (int s = 2 * h; s < 2 * h + 2; ++s)
            gload_lds16(gA + (size_t)(s * 64) * Kdim + ko,
                        &smem[bufo + s * 1024 + ldsAw]);
    };
    auto stageB = [&](int t, int h) {
        const int bufo = (t & 1) * BUF_BYTES;
        const size_t ko = (size_t)t * BKb;
#pragma unroll
        for (int s = 2 * h; s < 2 * h + 2; ++s)
            gload_lds16(gB + (size_t)(s * 64) * Kdim + ko,
                        &smem[bufo + s * 1024 + ldsBw]);
    };

    // fragment read bases: addr = kinst*8192 + kh*4096 + row*16
    const int aBase = kh * 4096 + wm * 2048 + lrow * 16;             // row=wm*128+mi*32+lrow
    const int bBase = 32768 + kh * 4096 + wn * 1024 + lrow * 16;     // row=wn*64+ni*32+lrow

    i32x16 acc[4][2] = {};          // [mi][ni], 16 i32 each
    i32x4 a01[2][4], a23[2][4], b0[4], b1[4];   // [mi][kinst] / [kinst]

#define RD_A01(P) do { _Pragma("unroll") for (int ki = 0; ki < 4; ++ki) \
    _Pragma("unroll") for (int mi = 0; mi < 2; ++mi) \
        a01[mi][ki] = *(const i32x4*)&smem[(P) + aBase + ki * 8192 + mi * 512]; } while (0)
#define RD_A23(P) do { _Pragma("unroll") for (int ki = 0; ki < 4; ++ki) \
    _Pragma("unroll") for (int mi = 0; mi < 2; ++mi) \
        a23[mi][ki] = *(const i32x4*)&smem[(P) + aBase + ki * 8192 + (2 + mi) * 512]; } while (0)
#define RD_B0(P) do { _Pragma("unroll") for (int ki = 0; ki < 4; ++ki) \
        b0[ki] = *(const i32x4*)&smem[(P) + bBase + ki * 8192]; } while (0)
#define RD_B1(P) do { _Pragma("unroll") for (int ki = 0; ki < 4; ++ki) \
        b1[ki] = *(const i32x4*)&smem[(P) + bBase + ki * 8192 + 512]; } while (0)

#define MFMA_Q(AF, BF, MO, NO) do { __builtin_amdgcn_s_setprio(1); \
    _Pragma("unroll") for (int ki = 0; ki < 4; ++ki) \
    _Pragma("unroll") for (int mi = 0; mi < 2; ++mi) \
        acc[(MO) + mi][NO] = __builtin_amdgcn_mfma_i32_32x32x32_i8( \
            AF[mi][ki], BF[ki], acc[(MO) + mi][NO], 0, 0, 0); \
    __builtin_amdgcn_s_setprio(0); } while (0)

    // ---- prologue: stage tile0 (8) + B(1) (4); confirm tile0; preload Q1 frags
    stageB(0, 0); stageB(0, 1); stageA(0, 0); stageA(0, 1);
    stageB(1, 0); stageB(1, 1);
    asm volatile("s_waitcnt vmcnt(4)" ::: "memory");   // tile0 landed
    __syncthreads();
    RD_A01(0); RD_B0(0);

#pragma unroll 1
    for (int t = 0; t < NKT; ++t) {
        const int p  = (t & 1) * BUF_BYTES;
        const int pn = ((t + 1) & 1) * BUF_BYTES;

        // ---- Q1: acc[0-1][0] = a01 x b0 ; b1 reads drain under MFMA ----
        LGKM0_FENCE();                         // a01,b0 (prefetched) landed
        RD_B1(p);
        if (t + 1 < NKT) stageA(t + 1, 0);
        __builtin_amdgcn_sched_barrier(0);
        MFMA_Q(a01, b0, 0, 0);

        // ---- Q2: acc[0-1][1] = a01 x b1 ; a23 reads drain under MFMA ----
        LGKM0_FENCE();                         // b1 landed
        RD_A23(p);
        if (t + 1 < NKT) stageA(t + 1, 1);
        __builtin_amdgcn_sched_barrier(0);
        MFMA_Q(a01, b1, 0, 1);
        __builtin_amdgcn_s_barrier();          // all waves' B-p reads complete
                                               // -> B-p region safely dead

        // ---- Q3: acc[2-3][0] = a23 x b0 ; stage B(t+2) into dead region ----
        LGKM0_FENCE();                         // a23 landed
        if (t + 2 < NKT) { stageB(t + 2, 0); stageB(t + 2, 1); }
        __builtin_amdgcn_sched_barrier(0);
        MFMA_Q(a23, b0, 2, 0);
        // counted wait: leave only B(t+2) in flight; t+1 fully landed
        if (t + 2 < NKT)      asm volatile("s_waitcnt vmcnt(4)" ::: "memory");
        else if (t + 1 < NKT) asm volatile("s_waitcnt vmcnt(0)" ::: "memory");
        __builtin_amdgcn_s_barrier();          // buffer pn ready for all waves

        // ---- Q4: acc[2-3][1] = a23 x b1 ; prefetch next-step Q1 frags ----
        if (t + 1 < NKT) { RD_A01(pn); RD_B0(pn); }
        __builtin_amdgcn_sched_barrier(0);
        MFMA_Q(a23, b1, 2, 1);
    }

    // ---- epilogue: 32x32 C/D col=lane&31, row=(r&3)+8*(r>>2)+4*(lane>>5) ----
    float bv[2];
#pragma unroll
    for (int ni = 0; ni < 2; ++ni)
        bv[ni] = rintf(bias[bn + wn * 64 + ni * 32 + lrow]);
#pragma unroll
    for (int mi = 0; mi < 4; ++mi) {
        const int rbase = bm + wm * 128 + mi * 32 + 4 * kh;
#pragma unroll
        for (int ni = 0; ni < 2; ++ni) {
            const int col = bn + wn * 64 + ni * 32 + lrow;
#pragma unroll
            for (int r = 0; r < 16; ++r) {
                const int row = rbase + (r & 3) + 8 * (r >> 2);
                out[(size_t)row * Ndim + col] = (float)acc[mi][ni][r] + bv[ni];
            }
        }
    }
}

extern "C" void kernel_launch(void* const* d_in, const int* in_sizes, int n_in,
                              void* d_out, int out_size, void* d_ws, size_t ws_size,
                              hipStream_t stream) {
    const int*   X32  = (const int*)d_in[0];   // [8192,4096] int8 values as int32
    const int*   W32  = (const int*)d_in[1];   // [4096,4096] int8 values as int32
    const float* bias = (const float*)d_in[2]; // [4096] fp32
    float* out = (float*)d_out;                // [8192,4096] fp32

    int8_t* Xp = (int8_t*)d_ws;                          // 32 MB
    int8_t* Wp = (int8_t*)d_ws + (size_t)Mdim * Kdim;    // 16 MB

    const int nX4 = Mdim * Kdim / 4;
    const int nW4 = Ndim * Kdim / 4;
    pack_i32_to_i8_both<<<4096, 256, 0, stream>>>(
        X32, W32, (unsigned int*)Xp, (unsigned int*)Wp, nX4, nX4 + nW4);

    dim3 grid(Mdim / BM, Ndim / BN);  // 32 x 16
    w8a8_gemm_256<<<grid, dim3(512), 0, stream>>>(Xp, Wp, bias, out);
}